// Round 10
// baseline (142.460 us; speedup 1.0000x reference)
//
#include <hip/hip_runtime.h>
#include <hip/hip_bf16.h>

#define IS 256
#define NEARV 0.1f
#define FARV 100.0f
#define NTX 16                     // 16x16 tiles of 16x16 px
#define NTILES 256
#define CAP 5120                   // per-tile entry capacity >= nf -> no overflow
#define CHK 32                     // entries per raster chunk
#define SLOTMAX (CAP / CHK)        // 160 chunk slots per tile
#define NSLOTS (NTILES * SLOTMAX)  // 40960 slots, one WAVE each
#define BINTH 128                  // threads per binning block
#define RBLOCKS (NSLOTS / 4)       // 10240 blocks of 4 waves

// ---------------- kernel 1: prep (unchanged from rounds 8-9, validated) ----------------
__global__ void kprep(const float* __restrict__ verts, const int* __restrict__ faces,
                      float4* __restrict__ fd, unsigned int* __restrict__ zb,
                      int* __restrict__ count, int nf) {
    int i = blockIdx.x * 256 + threadIdx.x;
    zb[i] = 0x42C80000u;  // __float_as_uint(100.0f); grid == IS*IS exactly
    if (i < NTILES) count[i] = 0;
    if (i >= nf) return;
    int i0 = faces[i * 3 + 0];
    int i1 = faces[i * 3 + 1];
    int i2 = faces[i * 3 + 2];
    // transform (v - eye; R == I exactly in fp32 for this camera)
    float z0 = verts[i0 * 3 + 2] + 2.7320508075688772f;
    float z1 = verts[i1 * 3 + 2] + 2.7320508075688772f;
    float z2 = verts[i2 * 3 + 2] + 2.7320508075688772f;
    bool front = (z0 > NEARV) && (z1 > NEARV) && (z2 > NEARV);
    float zs0 = (fabsf(z0) < 1e-5f) ? 1e-5f : z0;
    float zs1 = (fabsf(z1) < 1e-5f) ? 1e-5f : z1;
    float zs2 = (fabsf(z2) < 1e-5f) ? 1e-5f : z2;
    float d0 = zs0 * 0.57735026918962576f;  // zs * tan(30 deg)
    float d1 = zs1 * 0.57735026918962576f;
    float d2 = zs2 * 0.57735026918962576f;
    float x0 = verts[i0 * 3 + 0] / d0;
    float y0 = verts[i0 * 3 + 1] / d0;
    float x1 = verts[i1 * 3 + 0] / d1;
    float y1 = verts[i1 * 3 + 1] / d1;
    float x2 = verts[i2 * 3 + 0] / d2;
    float y2 = verts[i2 * 3 + 1] / d2;
    float area = (x1 - x0) * (y2 - y0) - (x2 - x0) * (y1 - y0);
    float4* o = fd + (size_t)i * 4;
    if (front && (fabsf(area) > 1e-8f)) {
        float xmin = fminf(x0, fminf(x1, x2));
        float xmax = fmaxf(x0, fmaxf(x1, x2));
        float ymin = fminf(y0, fminf(y1, y2));
        float ymax = fmaxf(y0, fmaxf(y1, y2));
        float ia = 1.0f / area;  // |area| > 1e-8 so area_s == area
        float iz0 = 1.0f / fmaxf(z0, 1e-4f);
        float iz1 = 1.0f / fmaxf(z1, 1e-4f);
        float iz2 = 1.0f / fmaxf(z2, 1e-4f);
        o[0] = make_float4(x0, y0, x1, y1);
        o[1] = make_float4(x2, y2, ia, iz0);
        o[2] = make_float4(iz1, iz2, 0.0f, 0.0f);
        o[3] = make_float4(xmin, ymin, xmax, ymax);
    } else {
        // sentinel bbox: fails the overlap predicate for every tile
        o[3] = make_float4(3.0e8f, 3.0e8f, -3.0e8f, -3.0e8f);
    }
}

// ---------------- kernel 2: bin (unchanged from rounds 8-9, validated) ----------------
// Entry layout per face (12 floats / 48 B): x0,y0,x1,y1,x2,y2,ia,iz0,iz1,iz2,pad,pad
__global__ void kbin(const float4* __restrict__ fd, int* __restrict__ count,
                     float4* __restrict__ list48, int nf) {
    __shared__ int scnt[NTILES];
    __shared__ int sbase[NTILES];
    const int tid = threadIdx.x;
    for (int t = tid; t < NTILES; t += BINTH) scnt[t] = 0;
    __syncthreads();
    const int f = blockIdx.x * BINTH + tid;
    int kx0 = 0, kx1 = -1, ky0 = 0, ky1 = -1;
    float4 bb = make_float4(0.f, 0.f, 0.f, 0.f);
    if (f < nf) {
        bb = fd[(size_t)f * 4 + 3];
        float tminx = fminf(fmaxf((bb.x * 256.0f + 225.0f) * (1.0f / 32.0f), -2.0f), 17.0f);
        float tmaxx = fminf(fmaxf((bb.z * 256.0f + 255.0f) * (1.0f / 32.0f), -2.0f), 17.0f);
        float tminy = fminf(fmaxf((bb.y * 256.0f + 225.0f) * (1.0f / 32.0f), -2.0f), 17.0f);
        float tmaxy = fminf(fmaxf((bb.w * 256.0f + 255.0f) * (1.0f / 32.0f), -2.0f), 17.0f);
        kx0 = max(0, (int)ceilf(tminx) - 1);
        kx1 = min(NTX - 1, (int)floorf(tmaxx) + 1);
        ky0 = max(0, (int)ceilf(tminy) - 1);
        ky1 = min(NTX - 1, (int)floorf(tmaxy) + 1);
    }
    // pass A: count
    for (int ky = ky0; ky <= ky1; ++ky) {
        float py_lo = (float)(32 * ky - 255) * (1.0f / 256.0f);
        float py_hi = (float)(32 * ky - 225) * (1.0f / 256.0f);
        if (!(bb.y <= py_hi && bb.w >= py_lo)) continue;
        for (int kx = kx0; kx <= kx1; ++kx) {
            float px_lo = (float)(32 * kx - 255) * (1.0f / 256.0f);
            float px_hi = (float)(32 * kx - 225) * (1.0f / 256.0f);
            if (bb.x <= px_hi && bb.z >= px_lo) atomicAdd(&scnt[ky * NTX + kx], 1);
        }
    }
    __syncthreads();
    for (int t = tid; t < NTILES; t += BINTH) {
        int c = scnt[t];
        sbase[t] = (c > 0) ? atomicAdd(&count[t], c) : 0;
        scnt[t] = 0;  // reuse as per-block cursor
    }
    __syncthreads();
    // pass B: scatter full 48B records (list order irrelevant: min is commutative)
    float4 r0, r1, r2;
    if (f < nf && ky1 >= ky0) {
        const float4* p = fd + (size_t)f * 4;
        r0 = p[0]; r1 = p[1]; r2 = p[2];
    }
    for (int ky = ky0; ky <= ky1; ++ky) {
        float py_lo = (float)(32 * ky - 255) * (1.0f / 256.0f);
        float py_hi = (float)(32 * ky - 225) * (1.0f / 256.0f);
        if (!(bb.y <= py_hi && bb.w >= py_lo)) continue;
        for (int kx = kx0; kx <= kx1; ++kx) {
            float px_lo = (float)(32 * kx - 255) * (1.0f / 256.0f);
            float px_hi = (float)(32 * kx - 225) * (1.0f / 256.0f);
            if (bb.x <= px_hi && bb.z >= px_lo) {
                int t = ky * NTX + kx;
                int slot = sbase[t] + atomicAdd(&scnt[t], 1);
                float4* dst = list48 + ((size_t)t * CAP + slot) * 3;
                dst[0] = r0; dst[1] = r1; dst[2] = r2;
            }
        }
    }
}

// SGPR broadcast of lane l's copy of v (l wave-uniform) -- bit-exact move.
__device__ __forceinline__ float rl(float v, int l) {
    return __uint_as_float(__builtin_amdgcn_readlane(__float_as_uint(v), (unsigned)l));
}

// ---------------- kernel 3: raster -- one wave per slot, readlane broadcast ----------------
// Wave w -> tile = w&255, slot = w>>8: every wave owns AT MOST ONE 32-entry
// chunk (the r8/r9 mapping gave waves up to 3 -> 96-entry serial chains ~50us).
// A hot tile's ~140 chunks land on ~140 distinct blocks. Empty waves cost one
// 1KB-table load. The chunk's 1536B is loaded ONCE cooperatively (3 x float2
// per lane, 24B/lane, single vmcnt wait), then the per-entry loop is
// MEMORY-FREE: 10 v_readlane broadcasts from lanes 2e/2e+1 + ~90 VALU of
// 4-way-ILP pixel math (expressions identical to rounds 1-9 -> bit-exact).
// Critical path ~ cold miss + 32 x ~200cyc ~ 3us (vs ~1200 cyc/entry before).
__launch_bounds__(256)
__global__ void kraster(const float4* __restrict__ list48, const int* __restrict__ count,
                        unsigned int* __restrict__ zb) {
    const int wid = blockIdx.x * 4 + (threadIdx.x >> 6);
    const int lane = threadIdx.x & 63;
    const int tile = wid & 255;
    const int slot = wid >> 8;

    const int cnt = count[tile];              // 1KB table -> L1 broadcast
    const int n = min(CHK, cnt - slot * CHK);
    if (n <= 0) return;                       // wave-uniform exit

    // cooperative chunk load: lane l holds entry floats [6l, 6l+6)
    const char* cbase = (const char*)list48 + ((size_t)tile * CAP + (size_t)slot * CHK) * 48;
    const float2* lp = (const float2*)(cbase + 24 * lane);  // 8B aligned
    float2 u0 = lp[0];
    float2 u1 = lp[1];
    float2 u2 = lp[2];   // trailing garbage for e >= n is never used (loop bound)

    const int cx = lane & 15;
    const int ry = lane >> 4;
    const int bx = tile & 15;
    const int by = tile >> 4;
    const int j = bx * 16 + cx;
    // pixel centers: (2*idx + 1 - 256)/256 (exact in fp32)
    const float px = ((float)(2 * j + 1) - 256.0f) * (1.0f / 256.0f);
    float py[4];
    int row[4];
#pragma unroll
    for (int r = 0; r < 4; ++r) {
        row[r] = by * 16 + ry + 4 * r;
        py[r] = ((float)(2 * row[r] + 1) - 256.0f) * (1.0f / 256.0f);
    }

    float mx[4] = {0.0f, 0.0f, 0.0f, 0.0f};

#pragma unroll 4
    for (int e = 0; e < n; ++e) {
        const int s0 = 2 * e, s1 = 2 * e + 1;  // uniform source lanes
        // entry e fields: lane s0 holds x0,y0,x1,y1,x2,y2; lane s1 holds ia,iz0,iz1,iz2
        float x0 = rl(u0.x, s0), y0 = rl(u0.y, s0);
        float x1 = rl(u1.x, s0), y1 = rl(u1.y, s0);
        float x2 = rl(u2.x, s0), y2 = rl(u2.y, s0);
        float ia = rl(u0.x, s1), iz0 = rl(u0.y, s1);
        float iz1 = rl(u1.x, s1), iz2 = rl(u1.y, s1);

        float dx0 = x0 - px, dx1 = x1 - px, dx2 = x2 - px;
#pragma unroll
        for (int r = 0; r < 4; ++r) {
            float dy0 = y0 - py[r], dy1 = y1 - py[r], dy2 = y2 - py[r];
            float e0 = dx1 * dy2 - dx2 * dy1;
            float e1 = dx2 * dy0 - dx0 * dy2;
            float w0 = e0 * ia;
            float w1 = e1 * ia;
            float w2 = 1.0f - w0 - w1;
            float invz = w0 * iz0 + w1 * iz1 + w2 * iz2;
            float invzc = fmaxf(invz, 1e-6f);
            // zp = 1/invzc; valid iff inside && NEAR < zp < FAR <=> 0.01 < invzc < 10
            bool ok = (w0 >= 0.0f) && (w1 >= 0.0f) && (w2 >= 0.0f) &&
                      (invzc < 10.0f) && (invzc > 0.01f);
            if (ok) mx[r] = fmaxf(mx[r], invzc);
        }
    }
#pragma unroll
    for (int r = 0; r < 4; ++r) {
        if (mx[r] > 0.0f) {
            float zp = 1.0f / mx[r];  // correctly-rounded 1/x is monotone => min-exact
            atomicMin(&zb[row[r] * IS + j], __float_as_uint(zp));
        }
    }
}

extern "C" void kernel_launch(void* const* d_in, const int* in_sizes, int n_in,
                              void* d_out, int out_size, void* d_ws, size_t ws_size,
                              hipStream_t stream) {
    const float* verts = (const float*)d_in[0];
    const int* faces = (const int*)d_in[1];
    unsigned int* zb = (unsigned int*)d_out;  // float bits, min'd in place

    const int nf = in_sizes[1] / 3;  // 5000 (<= CAP)

    char* ws = (char*)d_ws;
    size_t off = 0;
    float4* fd = (float4*)(ws + off);    off += (size_t)nf * 64;   // 320 KB
    off = (off + 255) & ~(size_t)255;
    int* count = (int*)(ws + off);       off += NTILES * 4;        // 1 KB
    off = (off + 255) & ~(size_t)255;
    float4* list48 = (float4*)(ws + off);  // 256 * 5120 * 48 B = 62.9 MB

    kprep<<<(IS * IS) / 256, 256, 0, stream>>>(verts, faces, fd, zb, count, nf);
    kbin<<<(nf + BINTH - 1) / BINTH, BINTH, 0, stream>>>(fd, count, list48, nf);
    kraster<<<RBLOCKS, 256, 0, stream>>>(list48, count, zb);
}

// Round 11
// 111.549 us; speedup vs baseline: 1.2771x; 1.2771x over previous
//
#include <hip/hip_runtime.h>
#include <hip/hip_bf16.h>

#define IS 256
#define NEARV 0.1f
#define FARV 100.0f
#define NTX 16                     // 16x16 tiles of 16x16 px
#define NTILES 256
#define CAP 5120                   // per-tile entry capacity >= nf -> no overflow
#define CHK 32                     // entries per raster chunk
#define BINTH 128                  // threads per binning block
#define RBLOCKS 1024               // small grid: dispatch is ~6ns/block (r2/r10 evidence)
#define RWAVES (RBLOCKS * 4)       // 4096 waves >= ~2500 items -> <=1 chunk/wave

// ---------------- kernel 1: prep (r8 verbatim + done-counter zero) ----------------
__global__ void kprep(const float* __restrict__ verts, const int* __restrict__ faces,
                      float4* __restrict__ fd, unsigned int* __restrict__ zb,
                      int* __restrict__ count, int nf) {
    int i = blockIdx.x * 256 + threadIdx.x;
    zb[i] = 0x42C80000u;  // __float_as_uint(100.0f); grid == IS*IS exactly
    if (i <= NTILES) count[i] = 0;  // 256 tile counts + count[256] = done counter
    if (i >= nf) return;
    int i0 = faces[i * 3 + 0];
    int i1 = faces[i * 3 + 1];
    int i2 = faces[i * 3 + 2];
    // transform (v - eye; R == I exactly in fp32 for this camera)
    float z0 = verts[i0 * 3 + 2] + 2.7320508075688772f;
    float z1 = verts[i1 * 3 + 2] + 2.7320508075688772f;
    float z2 = verts[i2 * 3 + 2] + 2.7320508075688772f;
    bool front = (z0 > NEARV) && (z1 > NEARV) && (z2 > NEARV);
    float zs0 = (fabsf(z0) < 1e-5f) ? 1e-5f : z0;
    float zs1 = (fabsf(z1) < 1e-5f) ? 1e-5f : z1;
    float zs2 = (fabsf(z2) < 1e-5f) ? 1e-5f : z2;
    float d0 = zs0 * 0.57735026918962576f;  // zs * tan(30 deg)
    float d1 = zs1 * 0.57735026918962576f;
    float d2 = zs2 * 0.57735026918962576f;
    float x0 = verts[i0 * 3 + 0] / d0;
    float y0 = verts[i0 * 3 + 1] / d0;
    float x1 = verts[i1 * 3 + 0] / d1;
    float y1 = verts[i1 * 3 + 1] / d1;
    float x2 = verts[i2 * 3 + 0] / d2;
    float y2 = verts[i2 * 3 + 1] / d2;
    float area = (x1 - x0) * (y2 - y0) - (x2 - x0) * (y1 - y0);
    float4* o = fd + (size_t)i * 4;
    if (front && (fabsf(area) > 1e-8f)) {
        float xmin = fminf(x0, fminf(x1, x2));
        float xmax = fmaxf(x0, fmaxf(x1, x2));
        float ymin = fminf(y0, fminf(y1, y2));
        float ymax = fmaxf(y0, fmaxf(y1, y2));
        float ia = 1.0f / area;  // |area| > 1e-8 so area_s == area
        float iz0 = 1.0f / fmaxf(z0, 1e-4f);
        float iz1 = 1.0f / fmaxf(z1, 1e-4f);
        float iz2 = 1.0f / fmaxf(z2, 1e-4f);
        o[0] = make_float4(x0, y0, x1, y1);
        o[1] = make_float4(x2, y2, ia, iz0);
        o[2] = make_float4(iz1, iz2, 0.0f, 0.0f);
        o[3] = make_float4(xmin, ymin, xmax, ymax);
    } else {
        // sentinel bbox: fails the overlap predicate for every tile
        o[3] = make_float4(3.0e8f, 3.0e8f, -3.0e8f, -3.0e8f);
    }
}

// ---------------- kernel 2: bin (r8 verbatim) + last-block item compaction ----------------
// After all blocks have finished their count-adds (device-scope done counter,
// __threadfence release before the add), the LAST block reads the final totals
// via coherent atomicAdd(.,0) and builds the compacted item list -- replacing
// round 6's separate 1-block kitems dispatch. items/nitems plain stores are
// made visible to kraster by the dispatch boundary.
__global__ void kbin(const float4* __restrict__ fd, int* __restrict__ count,
                     float4* __restrict__ list48, int* __restrict__ items,
                     int* __restrict__ nitems, int nf) {
    __shared__ int scnt[NTILES];
    __shared__ int sbase[NTILES];
    __shared__ int sdone;
    const int tid = threadIdx.x;
    for (int t = tid; t < NTILES; t += BINTH) scnt[t] = 0;
    __syncthreads();
    const int f = blockIdx.x * BINTH + tid;
    int kx0 = 0, kx1 = -1, ky0 = 0, ky1 = -1;
    float4 bb = make_float4(0.f, 0.f, 0.f, 0.f);
    if (f < nf) {
        bb = fd[(size_t)f * 4 + 3];
        float tminx = fminf(fmaxf((bb.x * 256.0f + 225.0f) * (1.0f / 32.0f), -2.0f), 17.0f);
        float tmaxx = fminf(fmaxf((bb.z * 256.0f + 255.0f) * (1.0f / 32.0f), -2.0f), 17.0f);
        float tminy = fminf(fmaxf((bb.y * 256.0f + 225.0f) * (1.0f / 32.0f), -2.0f), 17.0f);
        float tmaxy = fminf(fmaxf((bb.w * 256.0f + 255.0f) * (1.0f / 32.0f), -2.0f), 17.0f);
        kx0 = max(0, (int)ceilf(tminx) - 1);
        kx1 = min(NTX - 1, (int)floorf(tmaxx) + 1);
        ky0 = max(0, (int)ceilf(tminy) - 1);
        ky1 = min(NTX - 1, (int)floorf(tmaxy) + 1);
    }
    // pass A: count (exact predicate, same dyadic constants as rounds 1-10)
    for (int ky = ky0; ky <= ky1; ++ky) {
        float py_lo = (float)(32 * ky - 255) * (1.0f / 256.0f);
        float py_hi = (float)(32 * ky - 225) * (1.0f / 256.0f);
        if (!(bb.y <= py_hi && bb.w >= py_lo)) continue;
        for (int kx = kx0; kx <= kx1; ++kx) {
            float px_lo = (float)(32 * kx - 255) * (1.0f / 256.0f);
            float px_hi = (float)(32 * kx - 225) * (1.0f / 256.0f);
            if (bb.x <= px_hi && bb.z >= px_lo) atomicAdd(&scnt[ky * NTX + kx], 1);
        }
    }
    __syncthreads();
    for (int t = tid; t < NTILES; t += BINTH) {
        int c = scnt[t];
        sbase[t] = (c > 0) ? atomicAdd(&count[t], c) : 0;
        scnt[t] = 0;  // reuse as per-block cursor
    }
    __syncthreads();
    // pass B: scatter full 48B records (list order irrelevant: min is commutative)
    float4 r0, r1, r2;
    if (f < nf && ky1 >= ky0) {
        const float4* p = fd + (size_t)f * 4;
        r0 = p[0]; r1 = p[1]; r2 = p[2];
    }
    for (int ky = ky0; ky <= ky1; ++ky) {
        float py_lo = (float)(32 * ky - 255) * (1.0f / 256.0f);
        float py_hi = (float)(32 * ky - 225) * (1.0f / 256.0f);
        if (!(bb.y <= py_hi && bb.w >= py_lo)) continue;
        for (int kx = kx0; kx <= kx1; ++kx) {
            float px_lo = (float)(32 * kx - 255) * (1.0f / 256.0f);
            float px_hi = (float)(32 * kx - 225) * (1.0f / 256.0f);
            if (bb.x <= px_hi && bb.z >= px_lo) {
                int t = ky * NTX + kx;
                int slot = sbase[t] + atomicAdd(&scnt[t], 1);
                float4* dst = list48 + ((size_t)t * CAP + slot) * 3;
                dst[0] = r0; dst[1] = r1; dst[2] = r2;
            }
        }
    }
    // ---- last-done block builds the compacted item list ----
    __threadfence();  // release: order our count-adds before the done-add
    if (tid == 0) sdone = (atomicAdd(&count[NTILES], 1) == (int)gridDim.x - 1);
    __syncthreads();
    if (!sdone) return;
    __threadfence();  // acquire side
    for (int t = tid; t < NTILES; t += BINTH)
        scnt[t] = (atomicAdd(&count[t], 0) + CHK - 1) / CHK;  // coherent total -> nchunks
    __syncthreads();
    if (tid == 0) {
        int run = 0;
        for (int i = 0; i < NTILES; ++i) { sbase[i] = run; run += scnt[i]; }
        *nitems = run;  // plain store: visible to kraster via dispatch boundary
    }
    __syncthreads();
    for (int t = tid; t < NTILES; t += BINTH) {
        int off = sbase[t], n = scnt[t];
        for (int k = 0; k < n; ++k) items[off + k] = (t << 16) | k;
    }
}

// SGPR broadcast of lane l's copy of v (l wave-uniform) -- bit-exact move.
__device__ __forceinline__ float rl(float v, int l) {
    return __uint_as_float(__builtin_amdgcn_readlane(__float_as_uint(v), (unsigned)l));
}

// ---------------- kernel 3: raster ----------------
// 1024 blocks (small grid: co-resident in one dispatch generation). Wave i
// takes compacted item i (ni ~ 2500 < 4096 waves -> <=1 dense 32-entry chunk
// per wave; a hot tile's chunks land on distinct waves by construction).
// The chunk's 1536B is loaded once cooperatively (3 x float2 per lane, single
// vmcnt wait), then the per-entry loop is memory-free: 10 v_readlane
// broadcasts + ~90 VALU of 4-way-ILP pixel math (expressions identical to
// rounds 1-10 -> bit-exact, absmax 0.0 throughout). One atomicMin per pixel.
__launch_bounds__(256)
__global__ void kraster(const float4* __restrict__ list48, const int* __restrict__ count,
                        const int* __restrict__ items, const int* __restrict__ nitems,
                        unsigned int* __restrict__ zb) {
    const int wid = blockIdx.x * 4 + (threadIdx.x >> 6);
    const int lane = threadIdx.x & 63;
    const int ni = *nitems;
    const int cx = lane & 15;
    const int ry = lane >> 4;

    for (int it = wid; it < ni; it += RWAVES) {
        const int pk = items[it];
        const int tile = pk >> 16;
        const int chunk = pk & 0xffff;
        const int cnt = count[tile];          // final totals (atomically written)
        const int n = min(CHK, cnt - chunk * CHK);  // >= 1 by construction

        // cooperative chunk load: lane l holds entry floats [6l, 6l+6)
        const char* cbase = (const char*)list48 + ((size_t)tile * CAP + (size_t)chunk * CHK) * 48;
        const float2* lp = (const float2*)(cbase + 24 * lane);  // 8B aligned
        float2 u0 = lp[0];
        float2 u1 = lp[1];
        float2 u2 = lp[2];   // trailing garbage for e >= n never used (loop bound)

        const int bx = tile & 15;
        const int by = tile >> 4;
        const int j = bx * 16 + cx;
        // pixel centers: (2*idx + 1 - 256)/256 (exact in fp32)
        const float px = ((float)(2 * j + 1) - 256.0f) * (1.0f / 256.0f);
        float py[4];
        int row[4];
#pragma unroll
        for (int r = 0; r < 4; ++r) {
            row[r] = by * 16 + ry + 4 * r;
            py[r] = ((float)(2 * row[r] + 1) - 256.0f) * (1.0f / 256.0f);
        }

        float mx[4] = {0.0f, 0.0f, 0.0f, 0.0f};

#pragma unroll 4
        for (int e = 0; e < n; ++e) {
            const int s0 = 2 * e, s1 = 2 * e + 1;  // uniform source lanes
            // entry e fields: lane s0 holds x0,y0,x1,y1,x2,y2; lane s1 holds ia,iz0,iz1,iz2
            float x0 = rl(u0.x, s0), y0 = rl(u0.y, s0);
            float x1 = rl(u1.x, s0), y1 = rl(u1.y, s0);
            float x2 = rl(u2.x, s0), y2 = rl(u2.y, s0);
            float ia = rl(u0.x, s1), iz0 = rl(u0.y, s1);
            float iz1 = rl(u1.x, s1), iz2 = rl(u1.y, s1);

            float dx0 = x0 - px, dx1 = x1 - px, dx2 = x2 - px;
#pragma unroll
            for (int r = 0; r < 4; ++r) {
                float dy0 = y0 - py[r], dy1 = y1 - py[r], dy2 = y2 - py[r];
                float e0 = dx1 * dy2 - dx2 * dy1;
                float e1 = dx2 * dy0 - dx0 * dy2;
                float w0 = e0 * ia;
                float w1 = e1 * ia;
                float w2 = 1.0f - w0 - w1;
                float invz = w0 * iz0 + w1 * iz1 + w2 * iz2;
                float invzc = fmaxf(invz, 1e-6f);
                // zp = 1/invzc; valid iff inside && NEAR < zp < FAR <=> 0.01 < invzc < 10
                bool ok = (w0 >= 0.0f) && (w1 >= 0.0f) && (w2 >= 0.0f) &&
                          (invzc < 10.0f) && (invzc > 0.01f);
                if (ok) mx[r] = fmaxf(mx[r], invzc);
            }
        }
#pragma unroll
        for (int r = 0; r < 4; ++r) {
            if (mx[r] > 0.0f) {
                float zp = 1.0f / mx[r];  // correctly-rounded 1/x is monotone => min-exact
                atomicMin(&zb[row[r] * IS + j], __float_as_uint(zp));
            }
        }
    }
}

extern "C" void kernel_launch(void* const* d_in, const int* in_sizes, int n_in,
                              void* d_out, int out_size, void* d_ws, size_t ws_size,
                              hipStream_t stream) {
    const float* verts = (const float*)d_in[0];
    const int* faces = (const int*)d_in[1];
    unsigned int* zb = (unsigned int*)d_out;  // float bits, min'd in place

    const int nf = in_sizes[1] / 3;  // 5000 (<= CAP)

    char* ws = (char*)d_ws;
    size_t off = 0;
    float4* fd = (float4*)(ws + off);    off += (size_t)nf * 64;       // 320 KB
    off = (off + 255) & ~(size_t)255;
    int* count = (int*)(ws + off);       off += (NTILES + 1) * 4;      // 256 counts + done
    off = (off + 255) & ~(size_t)255;
    int* nitems = (int*)(ws + off);      off += 256;
    int* items = (int*)(ws + off);       off += (size_t)NTILES * (CAP / CHK) * 4;  // 160 KB
    off = (off + 255) & ~(size_t)255;
    float4* list48 = (float4*)(ws + off);  // 256 * 5120 * 48 B = 62.9 MB

    kprep<<<(IS * IS) / 256, 256, 0, stream>>>(verts, faces, fd, zb, count, nf);
    kbin<<<(nf + BINTH - 1) / BINTH, BINTH, 0, stream>>>(fd, count, list48, items, nitems, nf);
    kraster<<<RBLOCKS, 256, 0, stream>>>(list48, count, items, nitems, zb);
}